// Round 2
// baseline (1176.314 us; speedup 1.0000x reference)
//
#include <hip/hip_runtime.h>
#include <hip/hip_bf16.h>

// Dtype decision (round 2): reference is pure float32; harness maps float32 ->
// const float* / float* d_out. Round-1 NaN = reading f32 words as bf16 pairs.
// Internally we still run MFMA on bf16 hi/lo splits for speed + precision.

using short8   = __attribute__((ext_vector_type(8))) short;
using ushort4v = __attribute__((ext_vector_type(4))) unsigned short;
using f32x4    = __attribute__((ext_vector_type(4))) float;

#define L_T   2048
#define B_T   4
#define HID_T 512
#define HD_T  64
#define LQ_T  128
#define L0_T  1920   // L - LQ

__device__ __forceinline__ float b2f(unsigned short u){
  return __uint_as_float(((unsigned int)u) << 16);
}
__device__ __forceinline__ unsigned short f2b(float f){  // RNE float->bf16
  unsigned int u = __float_as_uint(f);
  u += 0x7FFFu + ((u >> 16) & 1u);
  return (unsigned short)(u >> 16);
}
__device__ __forceinline__ f32x4 mfma16(short8 a, short8 b, f32x4 c){
  return __builtin_amdgcn_mfma_f32_16x16x32_bf16(a, b, c, 0, 0, 0);
}

// ---------- split f32 -> bf16 hi/lo pair ----------
__global__ __launch_bounds__(256) void k_split(const float* __restrict__ x,
                                               unsigned short* __restrict__ hi,
                                               unsigned short* __restrict__ lo,
                                               int n4)
{
  int i = blockIdx.x * 256 + threadIdx.x;
  if (i >= n4) return;
  f32x4 v = ((const f32x4*)x)[i];
  ushort4v h4, l4;
  #pragma unroll
  for (int e = 0; e < 4; e++){
    unsigned short h = f2b(v[e]);
    h4[e] = h;
    l4[e] = f2b(v[e] - b2f(h));
  }
  ((ushort4v*)hi)[i] = h4;
  ((ushort4v*)lo)[i] = l4;
}

// ---------- projections: Y[(l,b)][o] = sum_h X[(l,b)][h] * W[o][h] ----------
// 3-pass hi/lo MFMA (XhiWhi + XloWhi + XhiWlo) ~ f32-faithful.
// mode 0: output split hi/lo bf16, layout [n][l][d]   (q, k)
// mode 1: output single bf16, transposed layout [n][d][l]   (v)
__global__ __launch_bounds__(256) void k_proj(const unsigned short* __restrict__ Xh,
                                              const unsigned short* __restrict__ Xl,
                                              const unsigned short* __restrict__ Wh,
                                              const unsigned short* __restrict__ Wl,
                                              unsigned short* __restrict__ ohi,
                                              unsigned short* __restrict__ olo,
                                              unsigned short* __restrict__ ovt,
                                              int mode)
{
  int wv = threadIdx.x >> 6, lane = threadIdx.x & 63;
  int tid = blockIdx.x * 4 + wv;           // 16384 wave-tiles
  int mt = tid >> 5, nt = tid & 31;
  int row0 = mt * 16, col0 = nt * 16;
  int lhi = lane >> 4, llo = lane & 15;
  const short* XH = (const short*)Xh;
  const short* XL = (const short*)Xl;
  const short* WH = (const short*)Wh;
  const short* WL = (const short*)Wl;
  f32x4 acc = {0.f, 0.f, 0.f, 0.f};
  int arow = row0 + llo, brow = col0 + llo;
  #pragma unroll 4
  for (int k0 = 0; k0 < 512; k0 += 32){
    int ao = arow * 512 + k0 + lhi * 8;
    int bo = brow * 512 + k0 + lhi * 8;
    short8 ah = *(const short8*)(XH + ao);
    short8 al = *(const short8*)(XL + ao);
    short8 bh = *(const short8*)(WH + bo);
    short8 bl = *(const short8*)(WL + bo);
    acc = mfma16(ah, bh, acc);
    acc = mfma16(al, bh, acc);
    acc = mfma16(ah, bl, acc);
  }
  #pragma unroll
  for (int r = 0; r < 4; r++){
    int row = row0 + lhi * 4 + r;          // flat (l,b): l = row/4, b = row%4
    int o   = col0 + llo;
    int l = row >> 2, bb = row & 3;
    int n = bb * 8 + (o >> 6), d = o & 63;
    float v = acc[r];
    if (mode == 0){
      size_t idx = ((size_t)n * L_T + l) * HD_T + d;
      unsigned short h = f2b(v);
      ohi[idx] = h;
      olo[idx] = f2b(v - b2f(h));
    } else {
      ovt[((size_t)n * HD_T + d) * L_T + l] = f2b(v);
    }
  }
}

// ---------- t[n][i][h] = sum_d Wk[(n%8)*64+d][h] * q_f32[n][1920+i][d] ----------
__global__ __launch_bounds__(256) void k_t(const unsigned short* __restrict__ qhi,
                                           const unsigned short* __restrict__ qlo,
                                           const float* __restrict__ Wk,
                                           float* __restrict__ tb)
{
  int n = blockIdx.z, i = blockIdx.y;
  int h = blockIdx.x * 256 + threadIdx.x;
  __shared__ float qv[64];
  if (threadIdx.x < 64){
    size_t qi = ((size_t)n * L_T + (L0_T + i)) * HD_T + threadIdx.x;
    qv[threadIdx.x] = b2f(qhi[qi]) + b2f(qlo[qi]);
  }
  __syncthreads();
  int kh = n & 7;
  float acc = 0.f;
  #pragma unroll 8
  for (int d = 0; d < 64; d++)
    acc += qv[d] * Wk[(kh * 64 + d) * 512 + h];
  tb[((size_t)n * LQ_T + i) * 512 + h] = acc;
}

// ---------- bias[n][i][j] = sum_h qrem[i][j][b][h] * t[n][i][h] ----------
__global__ __launch_bounds__(256) void k_bias(const float* __restrict__ tb,
                                              const float* __restrict__ qrem,
                                              float* __restrict__ bias)
{
  int bb = blockIdx.x & 3, i = blockIdx.x >> 2;
  __shared__ float ts[8][520];             // pad breaks bank conflicts
  for (int idx = threadIdx.x; idx < 8 * 512; idx += 256){
    int kh = idx >> 9, h = idx & 511;
    ts[kh][h] = tb[((size_t)(bb * 8 + kh) * LQ_T + i) * 512 + h];
  }
  __syncthreads();
  int kh = threadIdx.x & 7, j0 = threadIdx.x >> 3;
  for (int jj = 0; jj < 4; jj++){
    int j = j0 + jj * 32;
    const float* qr = qrem + (((size_t)i * LQ_T + j) * B_T + bb) * 512;
    float acc = 0.f;
    for (int h = 0; h < 512; h += 4){
      f32x4 v = *(const f32x4*)(qr + h);
      acc += v[0] * ts[kh][h] + v[1] * ts[kh][h + 1]
           + v[2] * ts[kh][h + 2] + v[3] * ts[kh][h + 3];
    }
    bias[((size_t)(bb * 8 + kh) * LQ_T + i) * LQ_T + j] = acc;
  }
}

// ---------- fused QK^T (hi/lo 3-pass) + bias + mask + softmax + f32 p-store ----------
// block = 1024 threads (16 waves): 16 query rows x 2048 keys, logits in registers.
__global__ __launch_bounds__(1024) void k_attn(const unsigned short* __restrict__ qhi,
                                               const unsigned short* __restrict__ qlo,
                                               const unsigned short* __restrict__ khi,
                                               const unsigned short* __restrict__ klo,
                                               const float* __restrict__ bias,
                                               const float* __restrict__ kpm,
                                               float* __restrict__ attnF)
{
  __shared__ char lds_raw[65536];
  float* red  = (float*)lds_raw;           // [16 waves][16 rows] (reduce phase)
  float* pbuf = (float*)lds_raw;           // [8][2048] f32 (store phase, 2 halves)
  int n = blockIdx.y, rb = blockIdx.x;
  int row0 = rb * 16;
  int w = threadIdx.x >> 6, lane = threadIdx.x & 63;
  int lhi = lane >> 4, llo = lane & 15;
  int bb = n >> 3;

  const short* qh = (const short*)qhi + ((size_t)n * L_T + row0) * HD_T;
  const short* ql = (const short*)qlo + ((size_t)n * L_T + row0) * HD_T;
  short8 ah[2], al[2];
  #pragma unroll
  for (int kk = 0; kk < 2; kk++){
    ah[kk] = *(const short8*)(qh + llo * 64 + kk * 32 + lhi * 8);
    al[kk] = *(const short8*)(ql + llo * 64 + kk * 32 + lhi * 8);
  }
  const short* kh_p = (const short*)khi + (size_t)n * L_T * HD_T;
  const short* kl_p = (const short*)klo + (size_t)n * L_T * HD_T;

  float sv[8][4];
  #pragma unroll
  for (int t = 0; t < 8; t++){
    int col0 = (w + t * 16) * 16;
    f32x4 acc = {0.f, 0.f, 0.f, 0.f};
    #pragma unroll
    for (int kk = 0; kk < 2; kk++){
      short8 bh = *(const short8*)(kh_p + (col0 + llo) * 64 + kk * 32 + lhi * 8);
      short8 bl = *(const short8*)(kl_p + (col0 + llo) * 64 + kk * 32 + lhi * 8);
      acc = mfma16(ah[kk], bh, acc);
      acc = mfma16(al[kk], bh, acc);
      acc = mfma16(ah[kk], bl, acc);
    }
    if (row0 >= L0_T && col0 >= L0_T){
      #pragma unroll
      for (int r = 0; r < 4; r++)
        acc[r] += bias[((size_t)n * LQ_T + (row0 - L0_T + lhi * 4 + r)) * LQ_T
                       + (col0 - L0_T + llo)];
    }
    float mk = (kpm[bb * L_T + col0 + llo] != 0.f) ? -__builtin_inff() : 0.f;
    #pragma unroll
    for (int r = 0; r < 4; r++)
      sv[t][r] = acc[r] * 0.125f + mk;     // (qk + bias)/sqrt(64) + log1p(-mask)
  }

  // ---- row max (lane owns rows lhi*4 .. lhi*4+3 of the 16-row block) ----
  float pm[4];
  #pragma unroll
  for (int r = 0; r < 4; r++){
    float m = sv[0][r];
    #pragma unroll
    for (int t = 1; t < 8; t++) m = fmaxf(m, sv[t][r]);
    #pragma unroll
    for (int msk = 1; msk < 16; msk <<= 1) m = fmaxf(m, __shfl_xor(m, msk));
    pm[r] = m;
  }
  if (llo == 0){
    #pragma unroll
    for (int r = 0; r < 4; r++) red[w * 16 + lhi * 4 + r] = pm[r];
  }
  __syncthreads();
  float rm[4];
  #pragma unroll
  for (int r = 0; r < 4; r++){
    float m = -__builtin_inff();
    for (int ww = 0; ww < 16; ww++) m = fmaxf(m, red[ww * 16 + lhi * 4 + r]);
    rm[r] = m;
  }
  __syncthreads();

  // ---- exp + row sum ----
  float ps[4] = {0.f, 0.f, 0.f, 0.f};
  #pragma unroll
  for (int t = 0; t < 8; t++){
    #pragma unroll
    for (int r = 0; r < 4; r++){
      float e = __expf(sv[t][r] - rm[r]);
      sv[t][r] = e;
      ps[r] += e;
    }
  }
  #pragma unroll
  for (int r = 0; r < 4; r++){
    float s = ps[r];
    #pragma unroll
    for (int msk = 1; msk < 16; msk <<= 1) s += __shfl_xor(s, msk);
    ps[r] = s;
  }
  if (llo == 0){
    #pragma unroll
    for (int r = 0; r < 4; r++) red[w * 16 + lhi * 4 + r] = ps[r];
  }
  __syncthreads();
  float ri[4];
  #pragma unroll
  for (int r = 0; r < 4; r++){
    float s = 0.f;
    for (int ww = 0; ww < 16; ww++) s += red[ww * 16 + lhi * 4 + r];
    ri[r] = 1.0f / s;
  }
  __syncthreads();

  // ---- f32 p store via LDS, two 8-row half passes (64 KB budget) ----
  #pragma unroll
  for (int half = 0; half < 2; half++){
    if ((lhi >> 1) == half){
      int rbase = (lhi & 1) * 4;
      #pragma unroll
      for (int t = 0; t < 8; t++){
        int col = (w + t * 16) * 16 + llo;
        #pragma unroll
        for (int r = 0; r < 4; r++)
          pbuf[(rbase + r) * 2048 + col] = sv[t][r] * ri[r];
      }
    }
    __syncthreads();
    size_t base = ((size_t)n * L_T + row0 + half * 8) * L_T;
    #pragma unroll
    for (int it = 0; it < 4; it++){
      int idx = it * 4096 + threadIdx.x * 4;
      *(f32x4*)(attnF + base + idx) = *(const f32x4*)(pbuf + idx);
    }
    __syncthreads();
  }
}

// ---------- PV: outbk[n][l][d] = sum_m p[n][l][m] * v[n][m][d] ----------
__global__ __launch_bounds__(256) void k_pv(const float* __restrict__ attnF,
                                            const unsigned short* __restrict__ vt,
                                            float* __restrict__ outbk)
{
  int wv = threadIdx.x >> 6, lane = threadIdx.x & 63;
  int tid = blockIdx.x * 4 + wv;           // 4096 wave-tiles: [n][rowtile]
  int n = tid >> 7, rt = tid & 127;
  int row0 = rt * 16;
  int lhi = lane >> 4, llo = lane & 15;
  const float* P = attnF + ((size_t)n * L_T + row0) * L_T;
  const short* V = (const short*)vt + (size_t)n * HD_T * L_T;
  f32x4 acc[4] = {{0,0,0,0},{0,0,0,0},{0,0,0,0},{0,0,0,0}};
  for (int k0 = 0; k0 < 2048; k0 += 32){
    const float* ap = P + llo * L_T + k0 + lhi * 8;
    f32x4 p0 = *(const f32x4*)ap;
    f32x4 p1 = *(const f32x4*)(ap + 4);
    short8 pa;
    #pragma unroll
    for (int e = 0; e < 4; e++){
      pa[e]     = (short)f2b(p0[e]);
      pa[e + 4] = (short)f2b(p1[e]);
    }
    #pragma unroll
    for (int c = 0; c < 4; c++){
      short8 b = *(const short8*)(V + (c * 16 + llo) * L_T + k0 + lhi * 8);
      acc[c] = mfma16(pa, b, acc[c]);
    }
  }
  #pragma unroll
  for (int c = 0; c < 4; c++)
    #pragma unroll
    for (int r = 0; r < 4; r++)
      outbk[((size_t)n * L_T + row0 + lhi * 4 + r) * HD_T + c * 16 + llo] = acc[c][r];
}

// ---------- final: y[(l,b)][o] = sum_c outbk_flat[(l,b)][c] * Wo[o][c] ----------
__global__ __launch_bounds__(256) void k_final(const float* __restrict__ outbk,
                                               const unsigned short* __restrict__ Wh,
                                               const unsigned short* __restrict__ Wl,
                                               float* __restrict__ y)
{
  int wv = threadIdx.x >> 6, lane = threadIdx.x & 63;
  int tid = blockIdx.x * 4 + wv;           // 16384 wave-tiles
  int mt = tid >> 5, nt = tid & 31;
  int row0 = mt * 16, col0 = nt * 16;
  int lhi = lane >> 4, llo = lane & 15;
  int arow = row0 + llo;
  int l = arow >> 2, bb = arow & 3;
  const short* WHs = (const short*)Wh;
  const short* WLs = (const short*)Wl;
  f32x4 acc = {0.f, 0.f, 0.f, 0.f};
  for (int k0 = 0; k0 < 512; k0 += 32){
    int c = k0 + lhi * 8;                  // 8 consecutive c within one head block
    const float* ap = outbk + ((size_t)(bb * 8 + (c >> 6)) * L_T + l) * HD_T + (c & 63);
    f32x4 a01 = *(const f32x4*)ap;
    f32x4 a23 = *(const f32x4*)(ap + 4);
    short8 ahi, alo;
    #pragma unroll
    for (int e = 0; e < 4; e++){
      unsigned short h0 = f2b(a01[e]);
      ahi[e] = (short)h0;  alo[e] = (short)f2b(a01[e] - b2f(h0));
      unsigned short h1 = f2b(a23[e]);
      ahi[e + 4] = (short)h1;  alo[e + 4] = (short)f2b(a23[e] - b2f(h1));
    }
    int bo = (col0 + llo) * 512 + k0 + lhi * 8;
    short8 bh = *(const short8*)(WHs + bo);
    short8 bl = *(const short8*)(WLs + bo);
    acc = mfma16(ahi, bh, acc);
    acc = mfma16(alo, bh, acc);
    acc = mfma16(ahi, bl, acc);
  }
  #pragma unroll
  for (int r = 0; r < 4; r++)
    y[(size_t)(row0 + lhi * 4 + r) * 512 + col0 + llo] = acc[r];
}

extern "C" void kernel_launch(void* const* d_in, const int* in_sizes, int n_in,
                              void* d_out, int out_size, void* d_ws, size_t ws_size,
                              hipStream_t stream)
{
  const float* query = (const float*)d_in[0];
  const float* key_t = (const float*)d_in[1];
  const float* value = (const float*)d_in[2];
  const float* kpm   = (const float*)d_in[3];
  const float* qrem  = (const float*)d_in[4];
  const float* Wq    = (const float*)d_in[5];
  const float* Wk    = (const float*)d_in[6];
  const float* Wv    = (const float*)d_in[7];
  const float* Wo    = (const float*)d_in[8];

  float* outY  = (float*)d_out;
  float* attnF = outY + (size_t)L_T * B_T * HID_T;           // 4,194,304 floats

  char* wp = (char*)d_ws;
  const size_t SZ_BK_BF16 = (size_t)32 * 2048 * 64 * 2;      // 8 MiB each
  unsigned short* qhi = (unsigned short*)wp; wp += SZ_BK_BF16;
  unsigned short* qlo = (unsigned short*)wp; wp += SZ_BK_BF16;
  unsigned short* khi = (unsigned short*)wp; wp += SZ_BK_BF16;
  unsigned short* klo = (unsigned short*)wp; wp += SZ_BK_BF16;
  unsigned short* vt  = (unsigned short*)wp; wp += SZ_BK_BF16;
  unsigned short* xh  = (unsigned short*)wp; wp += SZ_BK_BF16;
  unsigned short* xl  = (unsigned short*)wp; wp += SZ_BK_BF16;
  unsigned short* wh  = (unsigned short*)wp; wp += (size_t)512 * 512 * 2;
  unsigned short* wl  = (unsigned short*)wp; wp += (size_t)512 * 512 * 2;
  float* tbuf  = (float*)wp; wp += (size_t)32 * 128 * 512 * 4;
  float* biasb = (float*)wp; wp += (size_t)32 * 128 * 128 * 4;
  float* outbk = (float*)wp; wp += (size_t)32 * 2048 * 64 * 4;

  const int NX4 = (L_T * B_T * HID_T) / 4;   // 1,048,576
  const int NW4 = (HID_T * HID_T) / 4;       // 65,536

  // q projection
  k_split<<<NX4 / 256, 256, 0, stream>>>(query, xh, xl, NX4);
  k_split<<<NW4 / 256, 256, 0, stream>>>(Wq, wh, wl, NW4);
  k_proj<<<4096, 256, 0, stream>>>(xh, xl, wh, wl, qhi, qlo, nullptr, 0);
  // k projection
  k_split<<<NX4 / 256, 256, 0, stream>>>(key_t, xh, xl, NX4);
  k_split<<<NW4 / 256, 256, 0, stream>>>(Wk, wh, wl, NW4);
  k_proj<<<4096, 256, 0, stream>>>(xh, xl, wh, wl, khi, klo, nullptr, 0);
  // v projection (transposed single-bf16 output)
  k_split<<<NX4 / 256, 256, 0, stream>>>(value, xh, xl, NX4);
  k_split<<<NW4 / 256, 256, 0, stream>>>(Wv, wh, wl, NW4);
  k_proj<<<4096, 256, 0, stream>>>(xh, xl, wh, wl, nullptr, nullptr, vt, 1);

  k_t<<<dim3(2, 128, 32), 256, 0, stream>>>(qhi, qlo, Wk, tbuf);
  k_bias<<<512, 256, 0, stream>>>(tbuf, qrem, biasb);
  k_attn<<<dim3(128, 32), 1024, 0, stream>>>(qhi, qlo, khi, klo, biasb, kpm, attnF);
  k_pv<<<1024, 256, 0, stream>>>(attnF, vt, outbk);

  k_split<<<NW4 / 256, 256, 0, stream>>>(Wo, wh, wl, NW4);
  k_final<<<4096, 256, 0, stream>>>(outbk, wh, wl, outY);
}

// Round 3
// 1020.822 us; speedup vs baseline: 1.1523x; 1.1523x over previous
//
#include <hip/hip_runtime.h>
#include <hip/hip_bf16.h>

// Round 3: fuse PV into k_attn (kills k_pv's 537MB HBM re-read), nontemporal
// f32 p-stores overlapped with PV MFMA via XOR-swizzled LDS p-buffer,
// inline f32->bf16 hi/lo conversion in k_proj (drops 3 X-split kernels),
// single k_splitW for all 4 weight matrices. 12 launches -> 8.

using short8   = __attribute__((ext_vector_type(8))) short;
using ushort4v = __attribute__((ext_vector_type(4))) unsigned short;
using f32x4    = __attribute__((ext_vector_type(4))) float;

#define L_T   2048
#define B_T   4
#define HID_T 512
#define HD_T  64
#define LQ_T  128
#define L0_T  1920   // L - LQ

__device__ __forceinline__ float b2f(unsigned short u){
  return __uint_as_float(((unsigned int)u) << 16);
}
__device__ __forceinline__ unsigned short f2b(float f){  // RNE float->bf16
  unsigned int u = __float_as_uint(f);
  u += 0x7FFFu + ((u >> 16) & 1u);
  return (unsigned short)(u >> 16);
}
__device__ __forceinline__ f32x4 mfma16(short8 a, short8 b, f32x4 c){
  return __builtin_amdgcn_mfma_f32_16x16x32_bf16(a, b, c, 0, 0, 0);
}

// ---------- split all 4 weight matrices f32 -> bf16 hi/lo ----------
__global__ __launch_bounds__(256) void k_splitW(const float* __restrict__ w0,
                                                const float* __restrict__ w1,
                                                const float* __restrict__ w2,
                                                const float* __restrict__ w3,
                                                unsigned short* __restrict__ hi,
                                                unsigned short* __restrict__ lo)
{
  const float* src = (blockIdx.y == 0) ? w0 : (blockIdx.y == 1) ? w1
                   : (blockIdx.y == 2) ? w2 : w3;
  int i = blockIdx.x * 256 + threadIdx.x;          // 65536 f32x4 per W
  f32x4 v = ((const f32x4*)src)[i];
  ushort4v h4, l4;
  #pragma unroll
  for (int e = 0; e < 4; e++){
    unsigned short h = f2b(v[e]);
    h4[e] = h;
    l4[e] = f2b(v[e] - b2f(h));
  }
  size_t o = (size_t)blockIdx.y * 65536 + i;
  ((ushort4v*)hi)[o] = h4;
  ((ushort4v*)lo)[o] = l4;
}

// ---------- projections: Y[(l,b)][o] = sum_h X[(l,b)][h] * W[o][h] ----------
// X is f32 (converted to hi/lo in-register); W presplit bf16 hi/lo.
// 3-pass MFMA: XhiWhi + XloWhi + XhiWlo.
// mode 0: output split hi/lo bf16, layout [n][l][d]   (q, k)
// mode 1: output single bf16, transposed layout [n][d][l]   (v)
__global__ __launch_bounds__(256) void k_proj(const float* __restrict__ X,
                                              const unsigned short* __restrict__ Wh,
                                              const unsigned short* __restrict__ Wl,
                                              unsigned short* __restrict__ ohi,
                                              unsigned short* __restrict__ olo,
                                              unsigned short* __restrict__ ovt,
                                              int mode)
{
  int wv = threadIdx.x >> 6, lane = threadIdx.x & 63;
  int tid = blockIdx.x * 4 + wv;           // 16384 wave-tiles
  int mt = tid >> 5, nt = tid & 31;
  int row0 = mt * 16, col0 = nt * 16;
  int lhi = lane >> 4, llo = lane & 15;
  const short* WH = (const short*)Wh;
  const short* WL = (const short*)Wl;
  f32x4 acc = {0.f, 0.f, 0.f, 0.f};
  int arow = row0 + llo, brow = col0 + llo;
  #pragma unroll 4
  for (int k0 = 0; k0 < 512; k0 += 32){
    const float* ap = X + arow * 512 + k0 + lhi * 8;
    f32x4 a01 = *(const f32x4*)ap;
    f32x4 a23 = *(const f32x4*)(ap + 4);
    short8 ah, al;
    #pragma unroll
    for (int e = 0; e < 4; e++){
      unsigned short h0 = f2b(a01[e]);
      ah[e] = (short)h0;  al[e] = (short)f2b(a01[e] - b2f(h0));
      unsigned short h1 = f2b(a23[e]);
      ah[e + 4] = (short)h1;  al[e + 4] = (short)f2b(a23[e] - b2f(h1));
    }
    int bo = brow * 512 + k0 + lhi * 8;
    short8 bh = *(const short8*)(WH + bo);
    short8 bl = *(const short8*)(WL + bo);
    acc = mfma16(ah, bh, acc);
    acc = mfma16(al, bh, acc);
    acc = mfma16(ah, bl, acc);
  }
  #pragma unroll
  for (int r = 0; r < 4; r++){
    int row = row0 + lhi * 4 + r;          // flat (l,b): l = row/4, b = row%4
    int o   = col0 + llo;
    int l = row >> 2, bb = row & 3;
    int n = bb * 8 + (o >> 6), d = o & 63;
    float v = acc[r];
    if (mode == 0){
      size_t idx = ((size_t)n * L_T + l) * HD_T + d;
      unsigned short h = f2b(v);
      ohi[idx] = h;
      olo[idx] = f2b(v - b2f(h));
    } else {
      ovt[((size_t)n * HD_T + d) * L_T + l] = f2b(v);
    }
  }
}

// ---------- t[n][i][h] = sum_d Wk[(n%8)*64+d][h] * q_f32[n][1920+i][d] ----------
__global__ __launch_bounds__(256) void k_t(const unsigned short* __restrict__ qhi,
                                           const unsigned short* __restrict__ qlo,
                                           const float* __restrict__ Wk,
                                           float* __restrict__ tb)
{
  int n = blockIdx.z, i = blockIdx.y;
  int h = blockIdx.x * 256 + threadIdx.x;
  __shared__ float qv[64];
  if (threadIdx.x < 64){
    size_t qi = ((size_t)n * L_T + (L0_T + i)) * HD_T + threadIdx.x;
    qv[threadIdx.x] = b2f(qhi[qi]) + b2f(qlo[qi]);
  }
  __syncthreads();
  int kh = n & 7;
  float acc = 0.f;
  #pragma unroll 8
  for (int d = 0; d < 64; d++)
    acc += qv[d] * Wk[(kh * 64 + d) * 512 + h];
  tb[((size_t)n * LQ_T + i) * 512 + h] = acc;
}

// ---------- bias[n][i][j] = sum_h qrem[i][j][b][h] * t[n][i][h] ----------
__global__ __launch_bounds__(256) void k_bias(const float* __restrict__ tb,
                                              const float* __restrict__ qrem,
                                              float* __restrict__ bias)
{
  int bb = blockIdx.x & 3, i = blockIdx.x >> 2;
  __shared__ float ts[8][520];             // pad breaks bank conflicts
  for (int idx = threadIdx.x; idx < 8 * 512; idx += 256){
    int kh = idx >> 9, h = idx & 511;
    ts[kh][h] = tb[((size_t)(bb * 8 + kh) * LQ_T + i) * 512 + h];
  }
  __syncthreads();
  int kh = threadIdx.x & 7, j0 = threadIdx.x >> 3;
  for (int jj = 0; jj < 4; jj++){
    int j = j0 + jj * 32;
    const float* qr = qrem + (((size_t)i * LQ_T + j) * B_T + bb) * 512;
    float acc = 0.f;
    for (int h = 0; h < 512; h += 4){
      f32x4 v = *(const f32x4*)(qr + h);
      acc += v[0] * ts[kh][h] + v[1] * ts[kh][h + 1]
           + v[2] * ts[kh][h + 2] + v[3] * ts[kh][h + 3];
    }
    bias[((size_t)(bb * 8 + kh) * LQ_T + i) * LQ_T + j] = acc;
  }
}

// ---------- fused QK^T + bias + mask + softmax + p-store + PV ----------
// block = 1024 threads (16 waves): 16 query rows x 2048 keys.
// Phase A: QK (hi/lo 3-pass), logits in regs. Phase B: softmax reductions.
// Phase C: nontemporal f32 p stores (overlap) + bf16 p -> XOR-swizzled LDS.
// Phase D: PV MFMA, wave w owns K-slice [w*128, w*128+128). Phase E: LDS
// partial reduce (region reuse) -> outbk.
__global__ __launch_bounds__(1024, 4) void k_attn(const unsigned short* __restrict__ qhi,
                                                  const unsigned short* __restrict__ qlo,
                                                  const unsigned short* __restrict__ khi,
                                                  const unsigned short* __restrict__ klo,
                                                  const float* __restrict__ bias,
                                                  const float* __restrict__ kpm,
                                                  const unsigned short* __restrict__ vt,
                                                  float* __restrict__ attnF,
                                                  float* __restrict__ outbk)
{
  __shared__ __attribute__((aligned(16))) char lds[66560];
  float* partial = (float*)lds;                  // [16][16][64] f32 (phase E)
  float* red     = (float*)(lds + 65536);        // [16 waves][16 rows]
  int n = blockIdx.y, rb = blockIdx.x;
  int row0 = rb * 16;
  int w = threadIdx.x >> 6, lane = threadIdx.x & 63;
  int lhi = lane >> 4, llo = lane & 15;
  int bb = n >> 3;

  const short* qh = (const short*)qhi + ((size_t)n * L_T + row0) * HD_T;
  const short* ql = (const short*)qlo + ((size_t)n * L_T + row0) * HD_T;
  short8 ah[2], al[2];
  #pragma unroll
  for (int kk = 0; kk < 2; kk++){
    ah[kk] = *(const short8*)(qh + llo * 64 + kk * 32 + lhi * 8);
    al[kk] = *(const short8*)(ql + llo * 64 + kk * 32 + lhi * 8);
  }
  const short* kh_p = (const short*)khi + (size_t)n * L_T * HD_T;
  const short* kl_p = (const short*)klo + (size_t)n * L_T * HD_T;

  float sv[8][4];
  #pragma unroll
  for (int t = 0; t < 8; t++){
    int col0 = (w + t * 16) * 16;
    f32x4 acc = {0.f, 0.f, 0.f, 0.f};
    #pragma unroll
    for (int kk = 0; kk < 2; kk++){
      short8 bh = *(const short8*)(kh_p + (col0 + llo) * 64 + kk * 32 + lhi * 8);
      short8 bl = *(const short8*)(kl_p + (col0 + llo) * 64 + kk * 32 + lhi * 8);
      acc = mfma16(ah[kk], bh, acc);
      acc = mfma16(al[kk], bh, acc);
      acc = mfma16(ah[kk], bl, acc);
    }
    if (row0 >= L0_T && col0 >= L0_T){
      #pragma unroll
      for (int r = 0; r < 4; r++)
        acc[r] += bias[((size_t)n * LQ_T + (row0 - L0_T + lhi * 4 + r)) * LQ_T
                       + (col0 - L0_T + llo)];
    }
    float mk = (kpm[bb * L_T + col0 + llo] != 0.f) ? -__builtin_inff() : 0.f;
    #pragma unroll
    for (int r = 0; r < 4; r++)
      sv[t][r] = acc[r] * 0.125f + mk;     // (qk + bias)/sqrt(64) + log1p(-mask)
  }

  // ---- row max ----
  float pm[4];
  #pragma unroll
  for (int r = 0; r < 4; r++){
    float m = sv[0][r];
    #pragma unroll
    for (int t = 1; t < 8; t++) m = fmaxf(m, sv[t][r]);
    #pragma unroll
    for (int msk = 1; msk < 16; msk <<= 1) m = fmaxf(m, __shfl_xor(m, msk));
    pm[r] = m;
  }
  if (llo == 0){
    #pragma unroll
    for (int r = 0; r < 4; r++) red[w * 16 + lhi * 4 + r] = pm[r];
  }
  __syncthreads();
  float rm[4];
  #pragma unroll
  for (int r = 0; r < 4; r++){
    float m = -__builtin_inff();
    for (int ww = 0; ww < 16; ww++) m = fmaxf(m, red[ww * 16 + lhi * 4 + r]);
    rm[r] = m;
  }
  __syncthreads();

  // ---- exp + row sum ----
  float ps[4] = {0.f, 0.f, 0.f, 0.f};
  #pragma unroll
  for (int t = 0; t < 8; t++){
    #pragma unroll
    for (int r = 0; r < 4; r++){
      float e = __expf(sv[t][r] - rm[r]);
      sv[t][r] = e;
      ps[r] += e;
    }
  }
  #pragma unroll
  for (int r = 0; r < 4; r++){
    float s = ps[r];
    #pragma unroll
    for (int msk = 1; msk < 16; msk <<= 1) s += __shfl_xor(s, msk);
    ps[r] = s;
  }
  if (llo == 0){
    #pragma unroll
    for (int r = 0; r < 4; r++) red[w * 16 + lhi * 4 + r] = ps[r];
  }
  __syncthreads();
  float ri[4];
  #pragma unroll
  for (int r = 0; r < 4; r++){
    float s = 0.f;
    for (int ww = 0; ww < 16; ww++) s += red[ww * 16 + lhi * 4 + r];
    ri[r] = 1.0f / s;
  }
  __syncthreads();                         // red done before LDS reuse below

  // ---- phase C: nt f32 store (drains under PV) + bf16 p -> swizzled LDS ----
  size_t gbase = ((size_t)n * L_T + row0) * L_T;
  #pragma unroll
  for (int t = 0; t < 8; t++){
    int colb = (w + t * 16) * 16 + llo;
    #pragma unroll
    for (int r = 0; r < 4; r++){
      int row = lhi * 4 + r;
      float val = sv[t][r] * ri[r];
      __builtin_nontemporal_store(val, attnF + gbase + (size_t)row * L_T + colb);
      int byte = row * 4096 + ((colb * 2) ^ (row << 4));   // row<16
      *(unsigned short*)(lds + byte) = f2b(val);
    }
  }
  __syncthreads();

  // ---- phase D: PV. wave w: k in [w*128, w*128+128) ----
  const short* V = (const short*)vt + (size_t)n * HD_T * L_T;
  f32x4 pacc[4] = {{0,0,0,0},{0,0,0,0},{0,0,0,0},{0,0,0,0}};
  #pragma unroll
  for (int ks = 0; ks < 4; ks++){
    int kb = w * 128 + ks * 32;            // element offset in K dim
    int abyte = llo * 4096 + ((kb * 2 + lhi * 16) ^ (llo << 4));
    short8 a = *(const short8*)(lds + abyte);
    #pragma unroll
    for (int c = 0; c < 4; c++){
      short8 b = *(const short8*)(V + (c * 16 + llo) * L_T + kb + lhi * 8);
      pacc[c] = mfma16(a, b, pacc[c]);
    }
  }
  __syncthreads();                         // all p reads done before reuse

  // ---- phase E: cross-wave partial reduce via LDS ----
  #pragma unroll
  for (int c = 0; c < 4; c++)
    #pragma unroll
    for (int r = 0; r < 4; r++)
      partial[w * 1024 + (lhi * 4 + r) * 64 + c * 16 + llo] = pacc[c][r];
  __syncthreads();
  int orow = threadIdx.x >> 6, od = threadIdx.x & 63;
  float s = 0.f;
  #pragma unroll
  for (int ww = 0; ww < 16; ww++) s += partial[ww * 1024 + orow * 64 + od];
  outbk[((size_t)n * L_T + row0 + orow) * HD_T + od] = s;
}

// ---------- final: y[(l,b)][o] = sum_c outbk_flat[(l,b)][c] * Wo[o][c] ----------
__global__ __launch_bounds__(256) void k_final(const float* __restrict__ outbk,
                                               const unsigned short* __restrict__ Wh,
                                               const unsigned short* __restrict__ Wl,
                                               float* __restrict__ y)
{
  int wv = threadIdx.x >> 6, lane = threadIdx.x & 63;
  int tid = blockIdx.x * 4 + wv;           // 16384 wave-tiles
  int mt = tid >> 5, nt = tid & 31;
  int row0 = mt * 16, col0 = nt * 16;
  int lhi = lane >> 4, llo = lane & 15;
  int arow = row0 + llo;
  int l = arow >> 2, bb = arow & 3;
  const short* WHs = (const short*)Wh;
  const short* WLs = (const short*)Wl;
  f32x4 acc = {0.f, 0.f, 0.f, 0.f};
  for (int k0 = 0; k0 < 512; k0 += 32){
    int c = k0 + lhi * 8;                  // 8 consecutive c within one head block
    const float* ap = outbk + ((size_t)(bb * 8 + (c >> 6)) * L_T + l) * HD_T + (c & 63);
    f32x4 a01 = *(const f32x4*)ap;
    f32x4 a23 = *(const f32x4*)(ap + 4);
    short8 ahi, alo;
    #pragma unroll
    for (int e = 0; e < 4; e++){
      unsigned short h0 = f2b(a01[e]);
      ahi[e] = (short)h0;  alo[e] = (short)f2b(a01[e] - b2f(h0));
      unsigned short h1 = f2b(a23[e]);
      ahi[e + 4] = (short)h1;  alo[e + 4] = (short)f2b(a23[e] - b2f(h1));
    }
    int bo = (col0 + llo) * 512 + k0 + lhi * 8;
    short8 bh = *(const short8*)(WHs + bo);
    short8 bl = *(const short8*)(WLs + bo);
    acc = mfma16(ahi, bh, acc);
    acc = mfma16(alo, bh, acc);
    acc = mfma16(ahi, bl, acc);
  }
  #pragma unroll
  for (int r = 0; r < 4; r++)
    y[(size_t)(row0 + lhi * 4 + r) * 512 + col0 + llo] = acc[r];
}

extern "C" void kernel_launch(void* const* d_in, const int* in_sizes, int n_in,
                              void* d_out, int out_size, void* d_ws, size_t ws_size,
                              hipStream_t stream)
{
  const float* query = (const float*)d_in[0];
  const float* key_t = (const float*)d_in[1];
  const float* value = (const float*)d_in[2];
  const float* kpm   = (const float*)d_in[3];
  const float* qrem  = (const float*)d_in[4];
  const float* Wq    = (const float*)d_in[5];
  const float* Wk    = (const float*)d_in[6];
  const float* Wv    = (const float*)d_in[7];
  const float* Wo    = (const float*)d_in[8];

  float* outY  = (float*)d_out;
  float* attnF = outY + (size_t)L_T * B_T * HID_T;           // 4,194,304 floats

  char* wp = (char*)d_ws;
  const size_t SZ_BK_BF16 = (size_t)32 * 2048 * 64 * 2;      // 8 MiB each
  unsigned short* qhi = (unsigned short*)wp; wp += SZ_BK_BF16;
  unsigned short* qlo = (unsigned short*)wp; wp += SZ_BK_BF16;
  unsigned short* khi = (unsigned short*)wp; wp += SZ_BK_BF16;
  unsigned short* klo = (unsigned short*)wp; wp += SZ_BK_BF16;
  unsigned short* vt  = (unsigned short*)wp; wp += SZ_BK_BF16;
  unsigned short* whA = (unsigned short*)wp; wp += (size_t)4 * 512 * 512 * 2;
  unsigned short* wlA = (unsigned short*)wp; wp += (size_t)4 * 512 * 512 * 2;
  float* tbuf  = (float*)wp; wp += (size_t)32 * 128 * 512 * 4;
  float* biasb = (float*)wp; wp += (size_t)32 * 128 * 128 * 4;
  float* outbk = (float*)wp; wp += (size_t)32 * 2048 * 64 * 4;

  const size_t WSTEP = (size_t)512 * 512;    // elems per W

  k_splitW<<<dim3(256, 4), 256, 0, stream>>>(Wq, Wk, Wv, Wo, whA, wlA);
  k_proj<<<4096, 256, 0, stream>>>(query, whA + 0 * WSTEP, wlA + 0 * WSTEP,
                                   qhi, qlo, nullptr, 0);
  k_proj<<<4096, 256, 0, stream>>>(key_t, whA + 1 * WSTEP, wlA + 1 * WSTEP,
                                   khi, klo, nullptr, 0);
  k_proj<<<4096, 256, 0, stream>>>(value, whA + 2 * WSTEP, wlA + 2 * WSTEP,
                                   nullptr, nullptr, vt, 1);
  k_t<<<dim3(2, 128, 32), 256, 0, stream>>>(qhi, qlo, Wk, tbuf);
  k_bias<<<512, 256, 0, stream>>>(tbuf, qrem, biasb);
  k_attn<<<dim3(128, 32), 1024, 0, stream>>>(qhi, qlo, khi, klo, biasb, kpm,
                                             vt, attnF, outbk);
  k_final<<<4096, 256, 0, stream>>>(outbk, whA + 3 * WSTEP, wlA + 3 * WSTEP, outY);
}

// Round 5
// 562.987 us; speedup vs baseline: 2.0894x; 1.8132x over previous
//
#include <hip/hip_runtime.h>
#include <hip/hip_bf16.h>

// Round 5: swapped-operand QK^T (C[m][q], q lane-local) -> lane-local softmax,
// f32x4 p-stores, register-exact PV via v_mfma_f32_16x16x16_bf16 (p fragment
// matches K16 B-layout with NO data movement), persistent blocks + raw
// lgkmcnt-only barriers so p-stores drain under the next unit's QK.
// tr_read path from round 4 deleted (flat-pointer truncation bug).

using short8   = __attribute__((ext_vector_type(8))) short;
using short4v  = __attribute__((ext_vector_type(4))) short;
using ushort4v = __attribute__((ext_vector_type(4))) unsigned short;
using f32x4    = __attribute__((ext_vector_type(4))) float;

#define L_T   2048
#define B_T   4
#define HID_T 512
#define HD_T  64
#define LQ_T  128
#define L0_T  1920   // L - LQ

__device__ __forceinline__ float b2f(unsigned short u){
  return __uint_as_float(((unsigned int)u) << 16);
}
__device__ __forceinline__ unsigned short f2b(float f){  // RNE float->bf16
  unsigned int u = __float_as_uint(f);
  u += 0x7FFFu + ((u >> 16) & 1u);
  return (unsigned short)(u >> 16);
}
__device__ __forceinline__ f32x4 mfma16(short8 a, short8 b, f32x4 c){
  return __builtin_amdgcn_mfma_f32_16x16x32_bf16(a, b, c, 0, 0, 0);
}
#if __has_builtin(__builtin_amdgcn_mfma_f32_16x16x16bf16_1k)
__device__ __forceinline__ f32x4 mfma16k16(short4v a, short4v b, f32x4 c){
  return __builtin_amdgcn_mfma_f32_16x16x16bf16_1k(a, b, c, 0, 0, 0);
}
#else
__device__ __forceinline__ f32x4 mfma16k16(short4v a, short4v b, f32x4 c){
  f32x4 d;
  asm("v_mfma_f32_16x16x16_bf16 %0, %1, %2, %0"
      : "=v"(d) : "v"(a), "v"(b), "0"(c));
  return d;
}
#endif

// ---------- split X f32 -> packed bf16 hi/lo fragments ----------
__global__ __launch_bounds__(256) void k_splitX(const float* __restrict__ x,
                                                unsigned short* __restrict__ hi,
                                                unsigned short* __restrict__ lo)
{
  int chunk = blockIdx.x * 256 + threadIdx.x;      // 1,048,576 f32x4 chunks
  int flatrow = chunk >> 7;
  int hpos = (chunk & 127) * 4;
  f32x4 v = ((const f32x4*)x)[chunk];
  ushort4v h4, l4;
  #pragma unroll
  for (int e = 0; e < 4; e++){
    unsigned short h = f2b(v[e]);
    h4[e] = h;
    l4[e] = f2b(v[e] - b2f(h));
  }
  size_t idx = ((size_t)((flatrow >> 4) * 16 + (hpos >> 5))) * 512
             + (((hpos & 31) >> 3) * 16 + (flatrow & 15)) * 8 + (hpos & 7);
  *(ushort4v*)(hi + idx) = h4;
  *(ushort4v*)(lo + idx) = l4;
}

// ---------- split 4 weight matrices f32 -> packed bf16 hi/lo fragments ----
__global__ __launch_bounds__(256) void k_splitW(const float* __restrict__ w0,
                                                const float* __restrict__ w1,
                                                const float* __restrict__ w2,
                                                const float* __restrict__ w3,
                                                unsigned short* __restrict__ hi,
                                                unsigned short* __restrict__ lo)
{
  int wid = blockIdx.y;
  const float* src = (wid == 0) ? w0 : (wid == 1) ? w1 : (wid == 2) ? w2 : w3;
  int chunk = blockIdx.x * 256 + threadIdx.x;      // 65536 chunks
  int o = chunk >> 7;
  int hpos = (chunk & 127) * 4;
  f32x4 v = ((const f32x4*)src)[chunk];
  ushort4v h4, l4;
  #pragma unroll
  for (int e = 0; e < 4; e++){
    unsigned short h = f2b(v[e]);
    h4[e] = h;
    l4[e] = f2b(v[e] - b2f(h));
  }
  size_t idx = ((size_t)(wid * 512 + (o >> 4) * 16 + (hpos >> 5))) * 512
             + (((hpos & 31) >> 3) * 16 + (o & 15)) * 8 + (hpos & 7);
  *(ushort4v*)(hi + idx) = h4;
  *(ushort4v*)(lo + idx) = l4;
}

// ---------- projections from packed X,W. 16x64 tile per wave ----------
// mode 0: q/k-pack hi/lo: tile (n*128 + l>>4)*2 + (d>>5), lane ((d&31)>>3)*16+(l&15)
// mode 1: v-pack for K16 PV A-frags: tile ((n*128 + m>>4)*4 + d>>4),
//         slot ((m&15)>>2)*64 + (d&15)*4 + (m&3)
__global__ __launch_bounds__(256) void k_proj(const unsigned short* __restrict__ Xh,
                                              const unsigned short* __restrict__ Xl,
                                              const unsigned short* __restrict__ Wh,
                                              const unsigned short* __restrict__ Wl,
                                              unsigned short* __restrict__ ohi,
                                              unsigned short* __restrict__ olo,
                                              unsigned short* __restrict__ ovt,
                                              int mode)
{
  int wv = threadIdx.x >> 6, lane = threadIdx.x & 63;
  int tid = blockIdx.x * 4 + wv;           // 4096 wave-tiles
  int mt = tid >> 3, nt = tid & 7;
  int row0 = mt * 16, col0 = nt * 64;
  int lhi = lane >> 4, llo = lane & 15;
  const short* XH = (const short*)Xh;
  const short* XL = (const short*)Xl;
  const short* WH = (const short*)Wh;
  const short* WL = (const short*)Wl;
  f32x4 acc[4] = {{0,0,0,0},{0,0,0,0},{0,0,0,0},{0,0,0,0}};
  #pragma unroll 4
  for (int k0 = 0; k0 < 512; k0 += 32){
    int kk = k0 >> 5;
    size_t aidx = (size_t)(mt * 16 + kk) * 512 + lane * 8;
    short8 ah = *(const short8*)(XH + aidx);
    short8 al = *(const short8*)(XL + aidx);
    #pragma unroll
    for (int cb = 0; cb < 4; cb++){
      size_t bidx = (size_t)(((col0 >> 4) + cb) * 16 + kk) * 512 + lane * 8;
      short8 bh = *(const short8*)(WH + bidx);
      short8 bl = *(const short8*)(WL + bidx);
      acc[cb] = mfma16(ah, bh, acc[cb]);
      acc[cb] = mfma16(al, bh, acc[cb]);
      acc[cb] = mfma16(ah, bl, acc[cb]);
    }
  }
  #pragma unroll
  for (int cb = 0; cb < 4; cb++){
    #pragma unroll
    for (int r = 0; r < 4; r++){
      int row = row0 + lhi * 4 + r;        // flat (l,b)
      int o   = col0 + cb * 16 + llo;
      int l = row >> 2, bb = row & 3;
      int n = bb * 8 + (o >> 6), d = o & 63;
      float v = acc[cb][r];
      if (mode == 0){
        size_t idx = ((size_t)(n * 128 + (l >> 4)) * 2 + (d >> 5)) * 512
                   + (((d & 31) >> 3) * 16 + (l & 15)) * 8 + (d & 7);
        unsigned short h = f2b(v);
        ohi[idx] = h;
        olo[idx] = f2b(v - b2f(h));
      } else {
        int m = l;
        size_t idx = (((size_t)(n * 128 + (m >> 4)) * 4) + (d >> 4)) * 256
                   + ((m & 15) >> 2) * 64 + (d & 15) * 4 + (m & 3);
        ovt[idx] = f2b(v);
      }
    }
  }
}

// ---------- t[n][i][h] = sum_d Wk[(n%8)*64+d][h] * q_f32[n][1920+i][d] ----------
__global__ __launch_bounds__(256) void k_t(const unsigned short* __restrict__ qhi,
                                           const unsigned short* __restrict__ qlo,
                                           const float* __restrict__ Wk,
                                           float* __restrict__ tb)
{
  int n = blockIdx.z, i = blockIdx.y;
  int h = blockIdx.x * 256 + threadIdx.x;
  __shared__ float qv[64];
  if (threadIdx.x < 64){
    int d = threadIdx.x;
    int row = L0_T + i;
    size_t idx = ((size_t)(n * 128 + (row >> 4)) * 2 + (d >> 5)) * 512
               + (((d & 31) >> 3) * 16 + (row & 15)) * 8 + (d & 7);
    qv[d] = b2f(qhi[idx]) + b2f(qlo[idx]);
  }
  __syncthreads();
  int kh = n & 7;
  float acc = 0.f;
  #pragma unroll 8
  for (int d = 0; d < 64; d++)
    acc += qv[d] * Wk[(kh * 64 + d) * 512 + h];
  tb[((size_t)n * LQ_T + i) * 512 + h] = acc;
}

// ---------- bias[n][i][j] = sum_h qrem[i][j][b][h] * t[n][i][h] ----------
// wave-per-row: fully coalesced qrem f32x4 reads, conflict-free b128 LDS reads.
__global__ __launch_bounds__(256) void k_bias(const float* __restrict__ tb,
                                              const float* __restrict__ qrem,
                                              float* __restrict__ bias)
{
  int bb = blockIdx.x & 3, i = blockIdx.x >> 2;
  __shared__ float ts[8][512];
  for (int idx = threadIdx.x; idx < 4096; idx += 256){
    int kh = idx >> 9, h = idx & 511;
    ts[kh][h] = tb[((size_t)(bb * 8 + kh) * LQ_T + i) * 512 + h];
  }
  __syncthreads();
  int wv = threadIdx.x >> 6, lane = threadIdx.x & 63;
  for (int j = wv; j < 128; j += 4){
    const float* qr = qrem + (((size_t)i * LQ_T + j) * B_T + bb) * 512;
    f32x4 v0 = *(const f32x4*)(qr + lane * 4);
    f32x4 v1 = *(const f32x4*)(qr + 256 + lane * 4);
    float pl[8];
    #pragma unroll
    for (int kh = 0; kh < 8; kh++){
      f32x4 t0 = *(const f32x4*)&ts[kh][lane * 4];
      f32x4 t1 = *(const f32x4*)&ts[kh][256 + lane * 4];
      pl[kh] = v0[0]*t0[0] + v0[1]*t0[1] + v0[2]*t0[2] + v0[3]*t0[3]
             + v1[0]*t1[0] + v1[1]*t1[1] + v1[2]*t1[2] + v1[3]*t1[3];
    }
    #pragma unroll
    for (int kh = 0; kh < 8; kh++){
      float s = pl[kh];
      #pragma unroll
      for (int msk = 1; msk < 64; msk <<= 1) s += __shfl_xor(s, msk);
      pl[kh] = s;
    }
    if (lane == 0){
      #pragma unroll
      for (int kh = 0; kh < 8; kh++)
        bias[((size_t)(bb * 8 + kh) * LQ_T + i) * LQ_T + j] = pl[kh];
    }
  }
}

// ---------- fused QK^T(swapped) + bias + mask + softmax + p-store + PV ----------
// 1024 threads = 16 waves; persistent over units u = (n, rb).
// Wave w owns m-tiles {w + 16t}. C[m][q]: q = llo (lane-local!), m = lhi*4+r.
// Barriers are raw lgkmcnt-only: the 128KB f32 p-store of unit u drains under
// unit u+1's QK loads (no vmcnt(0) anywhere in the loop).
__global__ __launch_bounds__(1024, 4) void k_attn(
    const unsigned short* __restrict__ qhp, const unsigned short* __restrict__ qlp,
    const unsigned short* __restrict__ khp, const unsigned short* __restrict__ klp,
    const float* __restrict__ bias, const float* __restrict__ kpm,
    const unsigned short* __restrict__ vpk,
    float* __restrict__ attnF, float* __restrict__ outbk)
{
  __shared__ __attribute__((aligned(16))) float pf[16 * 1024];   // 64 KB
  __shared__ float2 red2[16 * 16];                               // 2 KB
  const int w = threadIdx.x >> 6, lane = threadIdx.x & 63;
  const int lhi = lane >> 4, llo = lane & 15;

  for (int u = blockIdx.x; u < 4096; u += gridDim.x){
    const int n = u >> 7, rb = u & 127;
    const int row0 = rb * 16, bb = n >> 3;

    const short* QH = (const short*)qhp + ((size_t)(n * 128 + rb) * 2) * 512 + lane * 8;
    const short* QL = (const short*)qlp + ((size_t)(n * 128 + rb) * 2) * 512 + lane * 8;
    short8 qh0 = *(const short8*)(QH);
    short8 qh1 = *(const short8*)(QH + 512);
    short8 ql0 = *(const short8*)(QL);
    short8 ql1 = *(const short8*)(QL + 512);
    const short* KH = (const short*)khp + (size_t)n * 131072 + w * 1024 + lane * 8;
    const short* KL = (const short*)klp + (size_t)n * 131072 + w * 1024 + lane * 8;

    // ---- QK^T: A = K-tile (rows = m), B = Q (cols = q) ----
    float sv[8][4];
    #pragma unroll
    for (int t = 0; t < 8; t++){
      f32x4 acc = {0.f, 0.f, 0.f, 0.f};
      short8 kh0v = *(const short8*)(KH + t * 16384);
      short8 kh1v = *(const short8*)(KH + t * 16384 + 512);
      short8 kl0v = *(const short8*)(KL + t * 16384);
      short8 kl1v = *(const short8*)(KL + t * 16384 + 512);
      acc = mfma16(kh0v, qh0, acc);
      acc = mfma16(kl0v, qh0, acc);
      acc = mfma16(kh0v, ql0, acc);
      acc = mfma16(kh1v, qh1, acc);
      acc = mfma16(kl1v, qh1, acc);
      acc = mfma16(kh1v, ql1, acc);
      if (t == 7 && rb >= 120 && w >= 8){
        int i  = row0 - L0_T + llo;
        int j0 = (w - 8) * 16 + lhi * 4;
        f32x4 bv = *(const f32x4*)(bias + ((size_t)(n * 128 + i)) * 128 + j0);
        acc += bv;
      }
      f32x4 mkv = *(const f32x4*)(kpm + bb * 2048 + (w + t * 16) * 16 + lhi * 4);
      #pragma unroll
      for (int r = 0; r < 4; r++)
        sv[t][r] = acc[r] * 0.125f + ((mkv[r] != 0.f) ? -__builtin_inff() : 0.f);
    }

    // ---- wave-level (max, expsum) for q = llo ----
    float pm = sv[0][0];
    #pragma unroll
    for (int t = 0; t < 8; t++)
      #pragma unroll
      for (int r = 0; r < 4; r++) pm = fmaxf(pm, sv[t][r]);
    pm = fmaxf(pm, __shfl_xor(pm, 16));
    pm = fmaxf(pm, __shfl_xor(pm, 32));
    float es = 0.f;
    #pragma unroll
    for (int t = 0; t < 8; t++)
      #pragma unroll
      for (int r = 0; r < 4; r++){
        float e = __expf(sv[t][r] - pm);
        sv[t][r] = e;
        es += e;
      }
    es += __shfl_xor(es, 16);
    es += __shfl_xor(es, 32);
    if (lane < 16) red2[w * 16 + llo] = make_float2(pm, es);
    asm volatile("s_waitcnt lgkmcnt(0)\n\ts_barrier" ::: "memory");   // b1

    // ---- cross-wave combine (4 pairs per lane + shfl over lhi) ----
    float2 c0 = red2[(lhi * 4 + 0) * 16 + llo];
    float2 c1 = red2[(lhi * 4 + 1) * 16 + llo];
    float2 c2 = red2[(lhi * 4 + 2) * 16 + llo];
    float2 c3 = red2[(lhi * 4 + 3) * 16 + llo];
    float mg = fmaxf(fmaxf(c0.x, c1.x), fmaxf(c2.x, c3.x));
    mg = fmaxf(mg, __shfl_xor(mg, 16));
    mg = fmaxf(mg, __shfl_xor(mg, 32));
    float cg = c0.y * __expf(c0.x - mg) + c1.y * __expf(c1.x - mg)
             + c2.y * __expf(c2.x - mg) + c3.y * __expf(c3.x - mg);
    cg += __shfl_xor(cg, 16);
    cg += __shfl_xor(cg, 32);
    float fac = __expf(pm - mg) / cg;

    // ---- p-store (f32x4, nontemporal) + register PV (K16 MFMA) ----
    float* aRow = attnF + ((size_t)(n * L_T + row0 + llo)) * L_T;
    const short* VP = (const short*)vpk + (size_t)n * 131072 + w * 1024 + lane * 4;
    f32x4 pacc0 = {0,0,0,0}, pacc1 = {0,0,0,0}, pacc2 = {0,0,0,0}, pacc3 = {0,0,0,0};
    #pragma unroll
    for (int t = 0; t < 8; t++){
      f32x4 pv;
      #pragma unroll
      for (int r = 0; r < 4; r++) pv[r] = sv[t][r] * fac;
      __builtin_nontemporal_store(pv, (f32x4*)(aRow + (w + t * 16) * 16 + lhi * 4));
      short4v pb;
      #pragma unroll
      for (int r = 0; r < 4; r++) pb[r] = (short)f2b(pv[r]);
      pacc0 = mfma16k16(*(const short4v*)(VP + t * 16384 +   0), pb, pacc0);
      pacc1 = mfma16k16(*(const short4v*)(VP + t * 16384 + 256), pb, pacc1);
      pacc2 = mfma16k16(*(const short4v*)(VP + t * 16384 + 512), pb, pacc2);
      pacc3 = mfma16k16(*(const short4v*)(VP + t * 16384 + 768), pb, pacc3);
    }

    // ---- cross-wave output reduce via pf (rotated slots, b128 writes) ----
    float* pfw = pf + w * 1024 + llo * 64;
    *(f32x4*)(pfw + (( 0 + lhi * 4 + llo * 4) & 63)) = pacc0;
    *(f32x4*)(pfw + ((16 + lhi * 4 + llo * 4) & 63)) = pacc1;
    *(f32x4*)(pfw + ((32 + lhi * 4 + llo * 4) & 63)) = pacc2;
    *(f32x4*)(pfw + ((48 + lhi * 4 + llo * 4) & 63)) = pacc3;
    asm volatile("s_waitcnt lgkmcnt(0)\n\ts_barrier" ::: "memory");   // b2
    {
      int q = w, d = lane;
      int slot = (d + q * 4) & 63;
      float s = 0.f;
      #pragma unroll
      for (int ww = 0; ww < 16; ww++) s += pf[ww * 1024 + q * 64 + slot];
      outbk[((size_t)(n * L_T + row0 + q)) * HD_T + d] = s;
    }
    // pf/red2 reuse across units is protected by b1/b2 (each region has a
    // full barrier between last read of unit u and first write of unit u+1).
  }
}

// ---------- final: y[(l,b)][o] = sum_c outbk_flat[(l,b)][c] * Wo[o][c] ----------
__global__ __launch_bounds__(256) void k_final(const float* __restrict__ outbk,
                                               const unsigned short* __restrict__ Wh,
                                               const unsigned short* __restrict__ Wl,
                                               float* __restrict__ y)
{
  int wv = threadIdx.x >> 6, lane = threadIdx.x & 63;
  int tid = blockIdx.x * 4 + wv;           // 16384 wave-tiles
  int mt = tid >> 5, nt = tid & 31;
  int row0 = mt * 16, col0 = nt * 16;
  int lhi = lane >> 4, llo = lane & 15;
  int arow = row0 + llo;
  int l = arow >> 2, bb = arow & 3;
  const short* WHs = (const short*)Wh;
  const short* WLs = (const short*)Wl;
  f32x4 acc = {0.f, 0.f, 0.f, 0.f};
  for (int k0 = 0; k0 < 512; k0 += 32){
    int c = k0 + lhi * 8;
    const float* ap = outbk + ((size_t)(bb * 8 + (c >> 6)) * L_T + l) * HD_T + (c & 63);
    f32x4 a01 = *(const f32x4*)ap;
    f32x4 a23 = *(const f32x4*)(ap + 4);
    short8 ahi, alo;
    #pragma unroll
    for (int e = 0; e < 4; e++){
      unsigned short h0 = f2b(a01[e]);
      ahi[e] = (short)h0;  alo[e] = (short)f2b(a01[e] - b2f(h0));
      unsigned short h1 = f2b(a23[e]);
      ahi[e + 4] = (short)h1;  alo[e + 4] = (short)f2b(a23[e] - b2f(h1));
    }
    size_t bidx = (size_t)(nt * 16 + (k0 >> 5)) * 512 + lane * 8;
    short8 bh = *(const short8*)(WHs + bidx);
    short8 bl = *(const short8*)(WLs + bidx);
    acc = mfma16(ahi, bh, acc);
    acc = mfma16(alo, bh, acc);
    acc = mfma16(ahi, bl, acc);
  }
  #pragma unroll
  for (int r = 0; r < 4; r++)
    y[(size_t)(row0 + lhi * 4 + r) * 512 + col0 + llo] = acc[r];
}

extern "C" void kernel_launch(void* const* d_in, const int* in_sizes, int n_in,
                              void* d_out, int out_size, void* d_ws, size_t ws_size,
                              hipStream_t stream)
{
  const float* query = (const float*)d_in[0];
  const float* key_t = (const float*)d_in[1];
  const float* value = (const float*)d_in[2];
  const float* kpm   = (const float*)d_in[3];
  const float* qrem  = (const float*)d_in[4];
  const float* Wq    = (const float*)d_in[5];
  const float* Wk    = (const float*)d_in[6];
  const float* Wv    = (const float*)d_in[7];
  const float* Wo    = (const float*)d_in[8];

  float* outY  = (float*)d_out;
  float* attnF = outY + (size_t)L_T * B_T * HID_T;

  char* wp = (char*)d_ws;
  const size_t SZ8M = (size_t)32 * 2048 * 64 * 2;            // 8 MiB
  unsigned short* qhp = (unsigned short*)wp; wp += SZ8M;
  unsigned short* qlp = (unsigned short*)wp; wp += SZ8M;
  unsigned short* khp = (unsigned short*)wp; wp += SZ8M;
  unsigned short* klp = (unsigned short*)wp; wp += SZ8M;
  unsigned short* vpk = (unsigned short*)wp; wp += SZ8M;
  unsigned short* whA = (unsigned short*)wp; wp += (size_t)4 * 512 * 512 * 2;
  unsigned short* wlA = (unsigned short*)wp; wp += (size_t)4 * 512 * 512 * 2;
  unsigned short* xh  = (unsigned short*)wp; wp += SZ8M;     // aliased by outbk
  unsigned short* xl  = (unsigned short*)wp; wp += SZ8M;     // aliased by outbk
  float* tbuf  = (float*)wp; wp += (size_t)32 * 128 * 512 * 4;
  float* biasb = (float*)wp; wp += (size_t)32 * 128 * 128 * 4;
  float* outbk = (float*)xh;               // 16 MiB, used only after projections

  const size_t WSTEP = (size_t)512 * 512;

  k_splitW<<<dim3(256, 4), 256, 0, stream>>>(Wq, Wk, Wv, Wo, whA, wlA);
  k_splitX<<<4096, 256, 0, stream>>>(query, xh, xl);
  k_proj<<<1024, 256, 0, stream>>>(xh, xl, whA + 0 * WSTEP, wlA + 0 * WSTEP,
                                   qhp, qlp, nullptr, 0);
  k_splitX<<<4096, 256, 0, stream>>>(key_t, xh, xl);
  k_proj<<<1024, 256, 0, stream>>>(xh, xl, whA + 1 * WSTEP, wlA + 1 * WSTEP,
                                   khp, klp, nullptr, 0);
  k_splitX<<<4096, 256, 0, stream>>>(value, xh, xl);
  k_proj<<<1024, 256, 0, stream>>>(xh, xl, whA + 2 * WSTEP, wlA + 2 * WSTEP,
                                   nullptr, nullptr, vpk, 1);
  k_t<<<dim3(2, 128, 32), 256, 0, stream>>>(qhp, qlp, Wk, tbuf);
  k_bias<<<512, 256, 0, stream>>>(tbuf, qrem, biasb);
  k_attn<<<512, 1024, 0, stream>>>(qhp, qlp, khp, klp, biasb, kpm,
                                   vpk, attnF, outbk);
  k_final<<<4096, 256, 0, stream>>>(outbk, whA + 3 * WSTEP, wlA + 3 * WSTEP, outY);
}